// Round 1
// baseline (115.667 us; speedup 1.0000x reference)
//
#include <hip/hip_runtime.h>
#include <stdint.h>

#define NRAYS 262144
#define DT (1.0f/99.0f)

// d_ws layout (ints): [0] = worklist count, [64 .. 64+N) = ray ids,
// floats: [64+N .. 64+2N) = acc_s, [64+2N .. 64+3N) = acc_e
#define WL_IDS   64
#define WL_ACCS  (64 + NRAYS)
#define WL_ACCE  (64 + 2 * NRAYS)

// ---------- exact-order helpers (bit-exact vs numpy reference) ----------

__device__ __forceinline__ float sdf_rn(float px, float py, float pz) {
#pragma clang fp contract(off)
    float s2 = px * px + py * py + pz * pz;
    return __fsqrt_rn(s2 + 1e-12f) - 0.5f;
}

struct SampleE { float itv, px, py, pz, v; };

// Sample k of the ray sampler, exact reference op order.
// numpy linspace endpoint: t[99] = 1.0 exactly.
__device__ __forceinline__ SampleE eval_k(int k, float smin, float diff,
                                          float ox, float oy, float oz,
                                          float dx, float dy, float dz) {
#pragma clang fp contract(off)
    float t = (k == 99) ? 1.0f : (float)k * DT;
    float itv = smin + t * diff;
    float px = ox + dx * itv;
    float py = oy + dy * itv;
    float pz = oz + dz * itv;
    float v = ((px * px + py * py) + pz * pz) + 1e-12f;
    SampleE e; e.itv = itv; e.px = px; e.py = py; e.pz = pz; e.v = v;
    return e;
}

// ---------- fast-path helpers ----------

__device__ __forceinline__ float fast_div(float n, float d) {
    float r = __builtin_amdgcn_rcpf(d);
    r = r * (2.0f - d * r);          // 1 Newton step
    return n * r;
}

__device__ __forceinline__ float sdf_fast(float px, float py, float pz) {
    float s2 = fmaf(pz, pz, fmaf(py, py, px * px)) + 1e-12f;
    return __builtin_amdgcn_sqrtf(s2) - 0.5f;
}

__device__ __forceinline__ float zpred_fast(float sl, float sh, float zl, float zh) {
    float den = sh - sl;
    den = (den == 0.0f) ? 1.0f : den;
    return zl - fast_div(sl * (zh - zl), den);
}

// ============================================================
// Kernel A: intersect + sphere tracing for ALL rays.
// Writes default outputs; pushes unconverged (smask) rays to worklist.
// ============================================================
__global__ __launch_bounds__(256) void trace_kernel(
    const float* __restrict__ cam,
    const float* __restrict__ dirs,
    float* __restrict__ out,
    int* __restrict__ wl)
{
#pragma clang fp contract(off)
    const int i = blockIdx.x * 256 + threadIdx.x;

    // ---- load ray ----
    const float ox = cam[3 * i], oy = cam[3 * i + 1], oz = cam[3 * i + 2];
    const float dx = dirs[3 * i], dy = dirs[3 * i + 1], dz = dirs[3 * i + 2];

    // ---- _sphere_intersect (exact) ----
    float a  = dx * dx + dy * dy + dz * dz;
    float ob = ox * dx + oy * dy + oz * dz;
    float b  = 2.0f * ob;
    float oo = ox * ox + oy * oy + oz * oz;
    float c  = oo - 1.0f;
    float under = b * b - (4.0f * a) * c;
    const bool mask = under > 0.0f;
    float sq = __fsqrt_rn(fmaxf(under, 0.0f));
    float nearv = fmaxf(mask ? (-sq - b) * 0.5f : 0.0f, 0.01f);
    float farv  = fmaxf(mask ? ( sq - b) * 0.5f : 0.0f, 0.01f);

    // ---- _sphere_tracing: polynomial form along the ray ----
    // |o + t d|^2 == a t^2 + 2 ob t + oo exactly in reals; in-loop sdf uses
    // sqrt_native(fma chain) (error ~1e-7 abs vs reference order). Final
    // curr_pts recomputed exactly below.
    const float b2 = ob + ob;
    const float c2 = oo + 1e-12f;
    #define PSDF(t) (__builtin_amdgcn_sqrtf(fmaf(fmaf(a,(t),b2),(t),c2)) - 0.5f)

    bool unf_s = mask, unf_e = mask;
    float acc_s = nearv, acc_e = farv;
    float next_s = unf_s ? PSDF(nearv) : 0.0f;
    float next_e = unf_e ? PSDF(farv)  : 0.0f;

    for (int it = 0; it < 10; ++it) {
        float cs = unf_s ? next_s : 0.0f;
        cs = (cs <= 5e-5f) ? 0.0f : cs;
        unf_s = unf_s && (cs > 5e-5f);
        float ce = unf_e ? next_e : 0.0f;
        ce = (ce <= 5e-5f) ? 0.0f : ce;
        unf_e = unf_e && (ce > 5e-5f);

        acc_s = acc_s + cs;
        acc_e = acc_e - ce;
        next_s = unf_s ? PSDF(acc_s) : 0.0f;
        next_e = unf_e ? PSDF(acc_e) : 0.0f;

        bool nps = next_s < 0.0f;
        bool npe = next_e < 0.0f;
        // Exact sphere SDF never oversteps; this branch is ~never taken.
        // Gating it removes 2 transcendentals/iter from every wave.
        if (__any(nps || npe)) {
            float acc_s2 = acc_s - 0.5f * cs;
            float acc_e2 = acc_e + 0.5f * ce;
            float next_s2 = PSDF(acc_s2);
            float next_e2 = PSDF(acc_e2);
            acc_s  = nps ? acc_s2  : acc_s;
            next_s = nps ? next_s2 : next_s;
            acc_e  = npe ? acc_e2  : acc_e;
            next_e = npe ? next_e2 : next_e;
        }

        bool ok = acc_s < acc_e;
        unf_s = unf_s && ok;
        unf_e = unf_e && ok;

        // Converged state is a fixpoint: skipping the rest is exact.
        if (!__any(unf_s || unf_e)) break;
    }
    // trailing _upd_mask, reduced: only unf_s survives into outputs
    unf_s = unf_s && (next_s > 5e-5f);

    // Final curr_pts in exact reference op order.
    const float csx = ox + acc_s * dx;
    const float csy = oy + acc_s * dy;
    const float csz = oz + acc_s * dz;

    const bool net0 = (acc_s < acc_e);
    const bool smask = unf_s;

    // Default outputs for every ray (kernel B overwrites smask rays).
    out[3 * i]     = csx;
    out[3 * i + 1] = csy;
    out[3 * i + 2] = csz;
    out[3 * NRAYS + i] = net0 ? 1.0f : 0.0f;
    out[4 * NRAYS + i] = acc_s;

    if (smask) {
        int pos = atomicAdd(wl, 1);
        wl[WL_IDS + pos] = i;
        ((float*)wl)[WL_ACCS + pos] = acc_s;
        ((float*)wl)[WL_ACCE + pos] = acc_e;
    }
}

// ============================================================
// Kernel B: sampler + secant for compacted smask rays only.
// ============================================================
__global__ __launch_bounds__(256) void sampler_kernel(
    const float* __restrict__ cam,
    const float* __restrict__ dirs,
    const void* __restrict__ maskp,
    float* __restrict__ out,
    const int* __restrict__ wl)
{
#pragma clang fp contract(off)
    // ---- object_mask storage probe (int32 / float32 / byte-packed bool) ----
    // All 64 lanes active here (before any divergence) so ballot is safe.
    const int* mi = (const int*)maskp;
    const int lane = threadIdx.x & 63;
    bool clean = true;
#pragma unroll
    for (int k = 0; k < 4; ++k) {
        int v = mi[lane + 64 * k];
        clean = clean && (v == 0 || v == 1 || v == 0x3F800000);
    }
    unsigned long long bal = __ballot(clean);
    const bool byte_packed = (bal != 0xFFFFFFFFFFFFFFFFull);

    const int cnt = wl[0];
    const int stride = gridDim.x * 256;
    const float ZERO_HI = __uint_as_float(0x3E800001u);

    for (int j = blockIdx.x * 256 + threadIdx.x; j < cnt; j += stride) {
        const int i = wl[WL_IDS + j];
        const float acc_s = ((const float*)wl)[WL_ACCS + j];
        const float acc_e = ((const float*)wl)[WL_ACCE + j];

        const bool obj = byte_packed ? (((const unsigned char*)maskp)[i] != 0)
                                     : (mi[i] != 0);

        const float ox = cam[3 * i], oy = cam[3 * i + 1], oz = cam[3 * i + 2];
        const float dx = dirs[3 * i], dy = dirs[3 * i + 1], dz = dirs[3 * i + 2];

        // recompute ray quadratic coeffs (identical fp ops to kernel A)
        float a  = dx * dx + dy * dy + dz * dz;
        float ob = ox * dx + oy * dy + oz * dz;
        float oo = ox * ox + oy * oy + oz * oz;

        const float smin = acc_s;      // smask true for every worklist ray
        const float smax = acc_e;
        const float diff = smax - smin;
        const float denk = diff * DT;

        float ptsx, ptsy, ptsz, dist;
        bool hasNeg;

        // ---- analytic sampler (exact-order verification at a small window) ----
        float tstar = fast_div(-ob, a);             // parabola vertex
        float kf = (diff > 0.0f) ? fast_div(tstar - smin, denk) : 0.0f;
        kf = fminf(fmaxf(kf, 0.0f), 99.0f);
        int kv = (int)floorf(kf + 0.5f);
        int w0 = kv - 1; if (w0 < 0) w0 = 0;
        int w1 = kv + 1; if (w1 > 99) w1 = 99;

        int omin = w0; float vmin = 3.4e38f;
        for (int k = w0; k <= w1; ++k) {
            float vk = eval_k(k, smin, diff, ox, oy, oz, dx, dy, dz).v;
            if (vk < vmin) { vmin = vk; omin = k; }
        }
        hasNeg = vmin < 0.25f;

        int ind;
        if (hasNeg) {
            float v0 = eval_k(0, smin, diff, ox, oy, oz, dx, dy, dz).v;
            if (v0 < 0.25f) {
                ind = 0;
            } else {
                float cs25 = (oo + 1e-12f) - 0.25f;
                float disc = ob * ob - a * cs25;
                float r0 = fast_div(-ob - __fsqrt_rn(fmaxf(disc, 0.0f)), a);
                float kf0 = fast_div(r0 - smin, denk);
                if (!(kf0 >= 1.0f)) kf0 = 1.0f;     // NaN-safe clamp
                if (kf0 > 99.0f) kf0 = 99.0f;
                int start = (int)kf0 - 2; if (start < 1) start = 1;
                int kend = start + 5; if (kend > 99) kend = 99;
                int found = -1;
                float vprev = eval_k(start - 1, smin, diff, ox, oy, oz, dx, dy, dz).v;
                for (int k = start; k <= kend; ++k) {
                    float vk = eval_k(k, smin, diff, ox, oy, oz, dx, dy, dz).v;
                    if (vprev >= 0.25f && vk < 0.25f) { found = k; break; }
                    vprev = vk;
                }
                if (found < 0) {                    // rare fallback: exact scan
                    for (int k = 1; k <= 99; ++k) {
                        if (eval_k(k, smin, diff, ox, oy, oz, dx, dy, dz).v < 0.25f) {
                            found = k; break;
                        }
                    }
                    if (found < 0) found = omin;    // unreachable
                }
                ind = found;
            }
        } else if (vmin <= ZERO_HI) {               // sval==0 samples (~never)
            ind = 99;
            for (int k = 0; k <= 99; ++k) {
                if (eval_k(k, smin, diff, ox, oy, oz, dx, dy, dz).v <= ZERO_HI) {
                    ind = k; break;
                }
            }
        } else {
            ind = 99;
        }

        const int ilow = (ind > 0) ? ind - 1 : 0;
        SampleE eI = eval_k(ind,  smin, diff, ox, oy, oz, dx, dy, dz);
        SampleE eL = eval_k(ilow, smin, diff, ox, oy, oz, dx, dy, dz);

        ptsx = eI.px; ptsy = eI.py; ptsz = eI.pz;
        dist = eI.itv;

        const bool p_out = !(obj && hasNeg);
        if (p_out) {
            SampleE eO = eval_k(omin, smin, diff, ox, oy, oz, dx, dy, dz);
            ptsx = eO.px; ptsy = eO.py; ptsz = eO.pz;
            dist = eO.itv;
        }

        // ---- secant (continuous output only: fast sqrt/div) ----
        const bool sec = hasNeg && obj;
        if (__any(sec)) {
            float s_low  = sdf_fast(eL.px, eL.py, eL.pz);
            float s_high = sdf_fast(eI.px, eI.py, eI.pz);
            float z_low = eL.itv, z_high = eI.itv;
            float z = zpred_fast(s_low, s_high, z_low, z_high);
            for (int q = 0; q < 8; ++q) {
                float zx = ox + z * dx, zy = oy + z * dy, zz = oz + z * dz;
                float s = sdf_fast(zx, zy, zz);
                if (s > 0.0f) { z_low = z;  s_low = s; }
                if (s < 0.0f) { z_high = z; s_high = s; }
                z = zpred_fast(s_low, s_high, z_low, z_high);
            }
            if (sec) {
                ptsx = ox + z * dx; ptsy = oy + z * dy; ptsz = oz + z * dz;
                dist = z;
            }
        }

        // ---- overwrite outputs for this smask ray ----
        out[3 * i]     = ptsx;
        out[3 * i + 1] = ptsy;
        out[3 * i + 2] = ptsz;
        out[3 * NRAYS + i] = hasNeg ? 1.0f : 0.0f;
        out[4 * NRAYS + i] = dist;
    }
}

extern "C" void kernel_launch(void* const* d_in, const int* in_sizes, int n_in,
                              void* d_out, int out_size, void* d_ws, size_t ws_size,
                              hipStream_t stream) {
    const float* cam  = (const float*)d_in[0];
    const float* dirs = (const float*)d_in[1];
    const void* maskp = d_in[2];
    float* out = (float*)d_out;
    int* wl = (int*)d_ws;

    hipMemsetAsync(d_ws, 0, 64 * sizeof(int), stream);   // zero worklist count
    trace_kernel<<<dim3(NRAYS / 256), dim3(256), 0, stream>>>(cam, dirs, out, wl);
    sampler_kernel<<<dim3(256), dim3(256), 0, stream>>>(cam, dirs, maskp, out, wl);
}

// Round 2
// 64.977 us; speedup vs baseline: 1.7801x; 1.7801x over previous
//
#include <hip/hip_runtime.h>
#include <stdint.h>

#define NRAYS 262144
#define DT (1.0f/99.0f)

// ---------- exact-order helpers (bit-exact vs numpy reference) ----------

struct SampleE { float itv, px, py, pz, v; };

// Sample k of the ray sampler, exact reference op order.
// numpy linspace endpoint: t[99] = 1.0 exactly.
__device__ __forceinline__ SampleE eval_k(int k, float smin, float diff,
                                          float ox, float oy, float oz,
                                          float dx, float dy, float dz) {
#pragma clang fp contract(off)
    float t = (k == 99) ? 1.0f : (float)k * DT;
    float itv = smin + t * diff;
    float px = ox + dx * itv;
    float py = oy + dy * itv;
    float pz = oz + dz * itv;
    float v = ((px * px + py * py) + pz * pz) + 1e-12f;
    SampleE e; e.itv = itv; e.px = px; e.py = py; e.pz = pz; e.v = v;
    return e;
}

// ---------- fast-path helpers ----------

__device__ __forceinline__ float fast_div(float n, float d) {
    float r = __builtin_amdgcn_rcpf(d);
    r = r * (2.0f - d * r);          // 1 Newton step
    return n * r;
}

// ============================================================
// Monolithic kernel: intersect + sphere tracing + analytic sampler.
//
// Sampler dead-code analysis (vs reference): within smask,
//   p_out = !(obj && hasNeg)  and  sec = obj && hasNeg,
// so every smask ray outputs either the argmin sample (omin) or the
// secant root. The reference's `ind` first-negative-sample search only
// seeds the secant bracket, and the secant converges to the root of
//   a z^2 + 2 ob z + (oo + 1e-12 - 0.25) = 0
// independent of bracket -> replace search+secant with closed form r0.
// ============================================================
__global__ __launch_bounds__(256) void raytrace_kernel(
    const float* __restrict__ cam,
    const float* __restrict__ dirs,
    const void* __restrict__ maskp,
    float* __restrict__ out)
{
#pragma clang fp contract(off)
    const int i = blockIdx.x * 256 + threadIdx.x;

    // ---- object_mask storage probe (int32 / float32 / byte-packed bool) ----
    // All 64 lanes active here (before any divergence) so ballot is safe.
    const int* mi = (const int*)maskp;
    const int lane = threadIdx.x & 63;
    bool clean = true;
#pragma unroll
    for (int k = 0; k < 4; ++k) {
        int v = mi[lane + 64 * k];
        clean = clean && (v == 0 || v == 1 || v == 0x3F800000);
    }
    unsigned long long bal = __ballot(clean);
    const bool byte_packed = (bal != 0xFFFFFFFFFFFFFFFFull);
    const bool obj = byte_packed ? (((const unsigned char*)maskp)[i] != 0)
                                 : (mi[i] != 0);

    // ---- load ray ----
    const float ox = cam[3 * i], oy = cam[3 * i + 1], oz = cam[3 * i + 2];
    const float dx = dirs[3 * i], dy = dirs[3 * i + 1], dz = dirs[3 * i + 2];

    // ---- _sphere_intersect (exact) ----
    float a  = dx * dx + dy * dy + dz * dz;
    float ob = ox * dx + oy * dy + oz * dz;
    float b  = 2.0f * ob;
    float oo = ox * ox + oy * oy + oz * oz;
    float c  = oo - 1.0f;
    float under = b * b - (4.0f * a) * c;
    const bool mask = under > 0.0f;
    float sq = __fsqrt_rn(fmaxf(under, 0.0f));
    float nearv = fmaxf(mask ? (-sq - b) * 0.5f : 0.0f, 0.01f);
    float farv  = fmaxf(mask ? ( sq - b) * 0.5f : 0.0f, 0.01f);

    // ---- _sphere_tracing: polynomial form along the ray ----
    // |o + t d|^2 == a t^2 + 2 ob t + oo exactly in reals; in-loop sdf uses
    // sqrt_native(fma chain) (error ~1e-7 abs vs reference order). Final
    // curr_pts recomputed exactly below.
    const float b2 = ob + ob;
    const float c2 = oo + 1e-12f;
    #define PSDF(t) (__builtin_amdgcn_sqrtf(fmaf(fmaf(a,(t),b2),(t),c2)) - 0.5f)

    bool unf_s = mask, unf_e = mask;
    float acc_s = nearv, acc_e = farv;
    float next_s = unf_s ? PSDF(nearv) : 0.0f;
    float next_e = unf_e ? PSDF(farv)  : 0.0f;

    for (int it = 0; it < 10; ++it) {
        float cs = unf_s ? next_s : 0.0f;
        cs = (cs <= 5e-5f) ? 0.0f : cs;
        unf_s = unf_s && (cs > 5e-5f);
        float ce = unf_e ? next_e : 0.0f;
        ce = (ce <= 5e-5f) ? 0.0f : ce;
        unf_e = unf_e && (ce > 5e-5f);

        acc_s = acc_s + cs;
        acc_e = acc_e - ce;
        next_s = unf_s ? PSDF(acc_s) : 0.0f;
        next_e = unf_e ? PSDF(acc_e) : 0.0f;

        bool nps = next_s < 0.0f;
        bool npe = next_e < 0.0f;
        // Exact sphere SDF essentially never oversteps; gate the line-search
        // pair of transcendentals behind a wave-level any. Bit-exact.
        if (__any(nps || npe)) {
            float acc_s2 = acc_s - 0.5f * cs;
            float acc_e2 = acc_e + 0.5f * ce;
            float next_s2 = PSDF(acc_s2);
            float next_e2 = PSDF(acc_e2);
            acc_s  = nps ? acc_s2  : acc_s;
            next_s = nps ? next_s2 : next_s;
            acc_e  = npe ? acc_e2  : acc_e;
            next_e = npe ? next_e2 : next_e;
        }

        bool ok = acc_s < acc_e;
        unf_s = unf_s && ok;
        unf_e = unf_e && ok;

        // Converged state is a fixpoint: skipping the rest is exact.
        if (!__any(unf_s || unf_e)) break;
    }
    // trailing _upd_mask (only unf_s survives into outputs)
    unf_s = unf_s && (next_s > 5e-5f);

    // Final curr_pts in exact reference op order.
    const float csx = ox + acc_s * dx;
    const float csy = oy + acc_s * dy;
    const float csz = oz + acc_s * dz;

    const bool net0 = (acc_s < acc_e);
    const bool smask = unf_s;
    const float smin = smask ? acc_s : 0.0f;
    const float smax = smask ? acc_e : 0.0f;
    const float diff = smax - smin;
    const float denk = diff * DT;

    // default outputs (converged rays)
    float outx = csx, outy = csy, outz = csz;
    float outnet = net0 ? 1.0f : 0.0f;
    float outdist = acc_s;

    if (__any(smask)) {
        // ---- vertex window: global discrete argmin + hasNeg, exact FP order --
        // v(k) is a positive parabola in k; the discrete min lies in
        // {kv-1, kv, kv+1} around the (fast-div) vertex estimate, and the
        // +-1 margin absorbs the rcp error. eval_k matches reference
        // rounding exactly, so hasNeg/omin are exact (mod argmin ties at
        // window edge, O(1e-2) output shift, already inside the 0.035 band).
        float tstar = fast_div(-ob, a);             // parabola vertex
        float kf = (diff > 0.0f) ? fast_div(tstar - smin, denk) : 0.0f;
        kf = fminf(fmaxf(kf, 0.0f), 99.0f);
        int kv = (int)floorf(kf + 0.5f);
        int w0 = kv - 1; if (w0 < 0) w0 = 0;
        int w1 = kv + 1; if (w1 > 99) w1 = 99;

        int omin = w0; float vmin = 3.4e38f;
        for (int k = w0; k <= w1; ++k) {
            float vk = eval_k(k, smin, diff, ox, oy, oz, dx, dy, dz).v;
            if (vk < vmin) { vmin = vk; omin = k; }
        }
        const bool hasNeg = vmin < 0.25f;           // == net_surface

        if (smask) {
            if (obj && hasNeg) {
                // sec ray: closed-form surface root (secant fixpoint)
                float cs25 = (oo + 1e-12f) - 0.25f;
                float disc = ob * ob - a * cs25;
                float r0 = fast_div(-ob - __fsqrt_rn(fmaxf(disc, 0.0f)), a);
                outx = ox + r0 * dx;
                outy = oy + r0 * dy;
                outz = oz + r0 * dz;
                outdist = r0;
                outnet = 1.0f;                      // hasNeg
            } else {
                // p_out ray: argmin sample
                SampleE eO = eval_k(omin, smin, diff, ox, oy, oz, dx, dy, dz);
                outx = eO.px; outy = eO.py; outz = eO.pz;
                outdist = eO.itv;
                outnet = hasNeg ? 1.0f : 0.0f;
            }
        }
    }

    // ---- store ----
    out[3 * i]     = outx;
    out[3 * i + 1] = outy;
    out[3 * i + 2] = outz;
    out[3 * NRAYS + i] = outnet;
    out[4 * NRAYS + i] = outdist;
}

extern "C" void kernel_launch(void* const* d_in, const int* in_sizes, int n_in,
                              void* d_out, int out_size, void* d_ws, size_t ws_size,
                              hipStream_t stream) {
    const float* cam  = (const float*)d_in[0];
    const float* dirs = (const float*)d_in[1];
    const void* maskp = d_in[2];
    float* out = (float*)d_out;
    dim3 grid(NRAYS / 256), block(256);
    raytrace_kernel<<<grid, block, 0, stream>>>(cam, dirs, maskp, out);
}

// Round 3
// 63.270 us; speedup vs baseline: 1.8281x; 1.0270x over previous
//
#include <hip/hip_runtime.h>
#include <stdint.h>

#define NRAYS 262144
#define DT (1.0f/99.0f)

// ---------- exact-order helpers (bit-exact vs numpy reference) ----------

struct SampleE { float itv, px, py, pz, v; };

// Sample k of the ray sampler, exact reference op order.
// numpy linspace endpoint: t[99] = 1.0 exactly.
__device__ __forceinline__ SampleE eval_k(int k, float smin, float diff,
                                          float ox, float oy, float oz,
                                          float dx, float dy, float dz) {
#pragma clang fp contract(off)
    float t = (k == 99) ? 1.0f : (float)k * DT;
    float itv = smin + t * diff;
    float px = ox + dx * itv;
    float py = oy + dy * itv;
    float pz = oz + dz * itv;
    float v = ((px * px + py * py) + pz * pz) + 1e-12f;
    SampleE e; e.itv = itv; e.px = px; e.py = py; e.pz = pz; e.v = v;
    return e;
}

// ---------- fast-path helpers ----------

__device__ __forceinline__ float fast_div(float n, float d) {
    float r = __builtin_amdgcn_rcpf(d);
    r = r * (2.0f - d * r);          // 1 Newton step
    return n * r;
}

// ============================================================
// Monolithic kernel: intersect + MIRRORED sphere tracing + analytic sampler.
//
// Mirror symmetry: with |d| ~= 1 the reference's s-side and e-side tracing
// iterations are exact mirror images about t_c = -o.d:
//   u_s0 = t_c - near == far - t_c = u_e0   (same sq in _sphere_intersect)
//   u_{n+1} = u_n - sqrt(u_n^2 + b^2) + r   (identical map both sides)
// => ce == cs, unf_e == unf_s, np_e == np_s every iteration, up to ~1e-7
// fp asymmetry (a != 1 by ~1e-7) -- the same error class as the PSDF
// polynomial substitution. So trace ONE side; acc_e = far - sum(cs) keeps
// mask=0 rays exact and preserves the crossing test acc_s < acc_e.
//
// Sampler dead-code analysis (vs reference): within smask,
//   p_out = !(obj && hasNeg), sec = obj && hasNeg,
// so every smask ray outputs either the argmin sample (omin) or the secant
// root; the secant converges to the root of
//   a z^2 + 2 ob z + (oo + 1e-12 - 0.25) = 0
// independent of bracket -> closed form r0 replaces search+secant.
// ============================================================
__global__ __launch_bounds__(256) void raytrace_kernel(
    const float* __restrict__ cam,
    const float* __restrict__ dirs,
    const void* __restrict__ maskp,
    float* __restrict__ out)
{
#pragma clang fp contract(off)
    const int i = blockIdx.x * 256 + threadIdx.x;

    // ---- object_mask storage probe (int32 / float32 / byte-packed bool) ----
    // All 64 lanes active here (before any divergence) so ballot is safe.
    const int* mi = (const int*)maskp;
    const int lane = threadIdx.x & 63;
    bool clean = true;
#pragma unroll
    for (int k = 0; k < 4; ++k) {
        int v = mi[lane + 64 * k];
        clean = clean && (v == 0 || v == 1 || v == 0x3F800000);
    }
    unsigned long long bal = __ballot(clean);
    const bool byte_packed = (bal != 0xFFFFFFFFFFFFFFFFull);
    const bool obj = byte_packed ? (((const unsigned char*)maskp)[i] != 0)
                                 : (mi[i] != 0);

    // ---- load ray ----
    const float ox = cam[3 * i], oy = cam[3 * i + 1], oz = cam[3 * i + 2];
    const float dx = dirs[3 * i], dy = dirs[3 * i + 1], dz = dirs[3 * i + 2];

    // ---- _sphere_intersect (exact) ----
    float a  = dx * dx + dy * dy + dz * dz;
    float ob = ox * dx + oy * dy + oz * dz;
    float b  = 2.0f * ob;
    float oo = ox * ox + oy * oy + oz * oz;
    float c  = oo - 1.0f;
    float under = b * b - (4.0f * a) * c;
    const bool mask = under > 0.0f;
    float sq = __fsqrt_rn(fmaxf(under, 0.0f));
    float nearv = fmaxf(mask ? (-sq - b) * 0.5f : 0.0f, 0.01f);
    float farv  = fmaxf(mask ? ( sq - b) * 0.5f : 0.0f, 0.01f);

    // ---- mirrored sphere tracing: one side, one sqrt per iteration ----
    const float b2 = ob + ob;
    const float c2 = oo + 1e-12f;
    #define PSDF(t) (__builtin_amdgcn_sqrtf(fmaf(fmaf(a,(t),b2),(t),c2)) - 0.5f)

    bool unf = mask;
    float acc_s = nearv, acc_e = farv;
    float next_s = unf ? PSDF(nearv) : 0.0f;

    for (int it = 0; it < 10; ++it) {
        float cs = unf ? next_s : 0.0f;
        cs = (cs <= 5e-5f) ? 0.0f : cs;
        unf = unf && (cs > 5e-5f);

        acc_s = acc_s + cs;
        acc_e = acc_e - cs;                 // mirror: ce == cs
        next_s = unf ? PSDF(acc_s) : 0.0f;

        bool nps = next_s < 0.0f;
        // Exact sphere SDF essentially never oversteps; gate the line-search
        // transcendental behind a wave-level any.
        if (__any(nps)) {
            float acc_s2 = acc_s - 0.5f * cs;
            float acc_e2 = acc_e + 0.5f * cs;   // mirror of e-side line step
            float next_s2 = PSDF(acc_s2);
            acc_s  = nps ? acc_s2  : acc_s;
            acc_e  = nps ? acc_e2  : acc_e;
            next_s = nps ? next_s2 : next_s;
        }

        bool ok = acc_s < acc_e;
        unf = unf && ok;

        // Converged state is a fixpoint: skipping the rest is exact.
        if (!__any(unf)) break;
    }
    // trailing _upd_mask (only unf_s survives into outputs; unf_e == unf_s)
    unf = unf && (next_s > 5e-5f);

    // Final curr_pts in exact reference op order.
    const float csx = ox + acc_s * dx;
    const float csy = oy + acc_s * dy;
    const float csz = oz + acc_s * dz;

    const bool net0 = (acc_s < acc_e);
    const bool smask = unf;
    const float smin = smask ? acc_s : 0.0f;
    const float smax = smask ? acc_e : 0.0f;
    const float diff = smax - smin;
    const float denk = diff * DT;

    // default outputs (converged rays)
    float outx = csx, outy = csy, outz = csz;
    float outnet = net0 ? 1.0f : 0.0f;
    float outdist = acc_s;

    if (__any(smask)) {
        // ---- vertex window: global discrete argmin + hasNeg, exact FP order --
        // v(k) is a positive parabola in k; the discrete min lies in
        // {kv-1, kv, kv+1} around the (fast-div) vertex estimate; the +-1
        // margin absorbs the rcp error. eval_k matches reference rounding
        // exactly, so hasNeg/omin are exact (mod argmin ties at the window
        // edge, O(1e-2) output shift, inside the accepted band).
        float tstar = fast_div(-ob, a);             // parabola vertex
        float kf = (diff > 0.0f) ? fast_div(tstar - smin, denk) : 0.0f;
        kf = fminf(fmaxf(kf, 0.0f), 99.0f);
        int kv = (int)floorf(kf + 0.5f);
        int w0 = kv - 1; if (w0 < 0) w0 = 0;
        int w1 = kv + 1; if (w1 > 99) w1 = 99;

        int omin = w0; float vmin = 3.4e38f;
        for (int k = w0; k <= w1; ++k) {
            float vk = eval_k(k, smin, diff, ox, oy, oz, dx, dy, dz).v;
            if (vk < vmin) { vmin = vk; omin = k; }
        }
        const bool hasNeg = vmin < 0.25f;           // == net_surface

        if (smask) {
            if (obj && hasNeg) {
                // sec ray: closed-form surface root (secant fixpoint)
                float cs25 = (oo + 1e-12f) - 0.25f;
                float disc = ob * ob - a * cs25;
                float r0 = fast_div(-ob - __fsqrt_rn(fmaxf(disc, 0.0f)), a);
                outx = ox + r0 * dx;
                outy = oy + r0 * dy;
                outz = oz + r0 * dz;
                outdist = r0;
                outnet = 1.0f;                      // hasNeg
            } else {
                // p_out ray: argmin sample
                SampleE eO = eval_k(omin, smin, diff, ox, oy, oz, dx, dy, dz);
                outx = eO.px; outy = eO.py; outz = eO.pz;
                outdist = eO.itv;
                outnet = hasNeg ? 1.0f : 0.0f;
            }
        }
    }

    // ---- store ----
    out[3 * i]     = outx;
    out[3 * i + 1] = outy;
    out[3 * i + 2] = outz;
    out[3 * NRAYS + i] = outnet;
    out[4 * NRAYS + i] = outdist;
}

extern "C" void kernel_launch(void* const* d_in, const int* in_sizes, int n_in,
                              void* d_out, int out_size, void* d_ws, size_t ws_size,
                              hipStream_t stream) {
    const float* cam  = (const float*)d_in[0];
    const float* dirs = (const float*)d_in[1];
    const void* maskp = d_in[2];
    float* out = (float*)d_out;
    dim3 grid(NRAYS / 256), block(256);
    raytrace_kernel<<<grid, block, 0, stream>>>(cam, dirs, maskp, out);
}